// Round 8
// baseline (505.960 us; speedup 1.0000x reference)
//
#include <hip/hip_runtime.h>
#include <hip/hip_bf16.h>

typedef __attribute__((ext_vector_type(8)))  short bf16x8;
typedef __attribute__((ext_vector_type(16))) float f32x16;
typedef __attribute__((ext_vector_type(4)))  float f32x4;
typedef __attribute__((ext_vector_type(2)))  __fp16 fp16x2;

#define NN 50000
#define EE 800000
#define HH 128
#define KK 320   /* 2H + B */
#define NEG 0.01f
#define NTILES (EE / 64)
#define NBLK 768            /* 256 CU x 3 resident blocks */
#define NSB 196             /* scan blocks: ceil(50000/256) */

#define MSG_BYTES   ((size_t)EE * HH * 2)        /* 204.8 MB f16 messages  */
#define FEATB_BYTES ((size_t)NN * HH * 2)        /* 12.8 MB bf16 feat      */
#define SLOT_BYTES  ((size_t)EE * 4)             /* 3.2 MB                 */
#define CNT_BYTES   ((size_t)50176 * 4)          /* padded to 256 blocks   */
#define ACC_BYTES   ((size_t)NN * HH * 2)        /* mid-fallback acc16     */

__device__ __forceinline__ unsigned pack2(float a, float b) {
    unsigned short lo = __builtin_bit_cast(unsigned short, __float2bfloat16(a));
    unsigned short hi = __builtin_bit_cast(unsigned short, __float2bfloat16(b));
    return (unsigned)lo | ((unsigned)hi << 16);
}

// ---------- feat f32 -> bf16 (3125 blocks x 256, exact) ----------
__global__ __launch_bounds__(256) void featcvt_kernel(const float* __restrict__ feat,
                                                      ushort* __restrict__ featb)
{
    const int t = blockIdx.x * 256 + threadIdx.x;
    const float* p = feat + (long long)t * 8;
    f32x4 v0 = *(const f32x4*)p;
    f32x4 v1 = *(const f32x4*)(p + 4);
    int4 h;
    h.x = (int)pack2(v0[0], v0[1]); h.y = (int)pack2(v0[2], v0[3]);
    h.z = (int)pack2(v1[0], v1[1]); h.w = (int)pack2(v1[2], v1[3]);
    *(int4*)(featb + (long long)t * 8) = h;
}

// ---------- CSR build ----------
__global__ __launch_bounds__(256) void hist_kernel(const int* __restrict__ dst,
                                                   unsigned* __restrict__ cnt)
{
    const int e = blockIdx.x * 256 + threadIdx.x;   // 3125 blocks, exact
    atomicAdd(&cnt[dst[e]], 1u);
}

__global__ __launch_bounds__(256) void scan1_kernel(const unsigned* __restrict__ cnt,
                                                    unsigned* __restrict__ base,
                                                    unsigned* __restrict__ bsum)
{
    __shared__ unsigned s[256];
    const int tid = threadIdx.x;
    const int g = blockIdx.x * 256 + tid;
    unsigned v = (g < NN) ? cnt[g] : 0u;
    s[tid] = v; __syncthreads();
    #pragma unroll
    for (int o = 1; o < 256; o <<= 1) {
        unsigned t = (tid >= o) ? s[tid - o] : 0u;
        __syncthreads();
        if (tid >= o) s[tid] += t;
        __syncthreads();
    }
    if (g < NN) base[g] = s[tid] - v;        // exclusive
    if (tid == 255) bsum[blockIdx.x] = s[255];
}

__global__ __launch_bounds__(256) void scan2_kernel(unsigned* __restrict__ bsum)
{
    __shared__ unsigned s[256];
    const int tid = threadIdx.x;
    unsigned v = (tid < NSB) ? bsum[tid] : 0u;
    s[tid] = v; __syncthreads();
    #pragma unroll
    for (int o = 1; o < 256; o <<= 1) {
        unsigned t = (tid >= o) ? s[tid - o] : 0u;
        __syncthreads();
        if (tid >= o) s[tid] += t;
        __syncthreads();
    }
    if (tid < NSB) bsum[tid] = s[tid] - v;   // exclusive block offsets
}

__global__ __launch_bounds__(256) void scan3_kernel(unsigned* __restrict__ base,
                                                    const unsigned* __restrict__ bsum)
{
    const int g = blockIdx.x * 256 + threadIdx.x;
    if (g < NN) base[g] += bsum[blockIdx.x];
}

__global__ __launch_bounds__(256) void slot_kernel(const int* __restrict__ dst,
                                                   const unsigned* __restrict__ base,
                                                   unsigned* __restrict__ cursor,
                                                   int* __restrict__ slot)
{
    const int e = blockIdx.x * 256 + threadIdx.x;   // 3125 blocks, exact
    const int d = dst[e];
    const unsigned rank = atomicAdd(&cursor[d], 1u);
    slot[e] = (int)(base[d] + rank);
}

// ---------- Phase A: MFMA pipeline, epilogue stores msg rows to CSR slots ----------
__global__ __launch_bounds__(256, 3) void fused_store_kernel(
    const ushort* __restrict__ featb, const float* __restrict__ gdf,
    const float*  __restrict__ W,     const float* __restrict__ bias,
    const int*    __restrict__ src,   const int*   __restrict__ dst,
    const int*    __restrict__ slot,  __fp16* __restrict__ msg)
{
    __shared__ char lds[64 * 640];
    __shared__ int  sslot[2][64];

    const int tid  = threadIdx.x;
    const int lane = tid & 63;
    const int wid  = tid >> 6;
    const int col  = wid * 32 + (lane & 31);
    const int khalf = lane >> 5;
    const int r = tid >> 2, q = tid & 3;

    bf16x8 Wb[20];
    {
        const float* wrow = W + col * KK + khalf * 8;
        #pragma unroll
        for (int k = 0; k < 20; k++) {
            f32x4 x0 = *(const f32x4*)(wrow + k * 16);
            f32x4 x1 = *(const f32x4*)(wrow + k * 16 + 4);
            union { bf16x8 v; unsigned u[4]; } t;
            t.u[0] = pack2(x0[0], x0[1]); t.u[1] = pack2(x0[2], x0[3]);
            t.u[2] = pack2(x1[0], x1[1]); t.u[3] = pack2(x1[2], x1[3]);
            Wb[k] = t.v;
        }
    }
    const float bv = bias[col];

    int4  sf[8];
    f32x4 sgv[4];
    int   slStage;

    auto issueLoads = [&](long long t, int s_i, int d_i) {
        const ushort* fs = featb + (long long)s_i * HH;
        const ushort* fd = featb + (long long)d_i * HH;
        const float*  ge = gdf + (t * 64 + r) * 64;
        #pragma unroll
        for (int i = 0; i < 8; i++) {
            const int c = q + i * 4;
            sf[i] = *(const int4*)((c < 16) ? (fs + c * 8) : (fd + (c - 16) * 8));
        }
        #pragma unroll
        for (int i = 0; i < 2; i++) {
            const int cg = q + i * 4;
            sgv[2 * i]     = *(const f32x4*)(ge + cg * 8);
            sgv[2 * i + 1] = *(const f32x4*)(ge + cg * 8 + 4);
        }
    };
    auto writeStage = [&](int buf) {
        const int xr = (r & 7) << 4;
        #pragma unroll
        for (int i = 0; i < 8; i++) {
            const int c = q + i * 4;
            *(int4*)(lds + r * 640 + ((c * 16) ^ xr)) = sf[i];
        }
        #pragma unroll
        for (int i = 0; i < 2; i++) {
            const int c = 32 + q + i * 4;
            int4 h;
            h.x = (int)pack2(sgv[2*i][0], sgv[2*i][1]);
            h.y = (int)pack2(sgv[2*i][2], sgv[2*i][3]);
            h.z = (int)pack2(sgv[2*i+1][0], sgv[2*i+1][1]);
            h.w = (int)pack2(sgv[2*i+1][2], sgv[2*i+1][3]);
            *(int4*)(lds + r * 640 + ((c * 16) ^ xr)) = h;
        }
        if (q == 0) sslot[buf][r] = slStage;
    };

    int tile = blockIdx.x;
    {
        int s0 = src[(long long)tile * 64 + r];
        int d0 = dst[(long long)tile * 64 + r];
        issueLoads(tile, s0, d0);
        slStage = slot[(long long)tile * 64 + r];
    }
    int nt = tile + NBLK;
    int sN, dN, slN;
    {
        const long long tc = (nt < NTILES) ? nt : 0;
        sN = src[tc * 64 + r]; dN = dst[tc * 64 + r]; slN = slot[tc * 64 + r];
    }
    writeStage(0);
    asm volatile("s_waitcnt lgkmcnt(0)" ::: "memory");
    __builtin_amdgcn_sched_barrier(0);
    __builtin_amdgcn_s_barrier();

    const int arow = lane & 31;
    const int xa   = (arow & 7) << 4;
    int cur = 0;

    while (true) {
        const bool hasNext = (nt < NTILES);
        if (hasNext) {
            issueLoads(nt, sN, dN);
            slStage = slN;
            const long long tc = (nt + NBLK < NTILES) ? (long long)(nt + NBLK) : 0;
            sN = src[tc * 64 + r]; dN = dst[tc * 64 + r]; slN = slot[tc * 64 + r];
        }

        f32x16 acc0 = {}; f32x16 acc1 = {};
        #pragma unroll
        for (int k = 0; k < 20; k++) {
            const int kb = k * 32 + khalf * 16;
            bf16x8 a0 = *(const bf16x8*)(lds + arow * 640 + (kb ^ xa));
            bf16x8 a1 = *(const bf16x8*)(lds + (arow + 32) * 640 + (kb ^ xa));
            acc0 = __builtin_amdgcn_mfma_f32_32x32x16_bf16(a0, Wb[k], acc0, 0, 0, 0);
            acc1 = __builtin_amdgcn_mfma_f32_32x32x16_bf16(a1, Wb[k], acc1, 0, 0, 0);
        }

        if (hasNext) {
            __builtin_amdgcn_s_barrier();
            __builtin_amdgcn_sched_barrier(0);
            writeStage(cur ^ 1);
            asm volatile("s_waitcnt lgkmcnt(0)" ::: "memory");
            __builtin_amdgcn_sched_barrier(0);
            __builtin_amdgcn_s_barrier();
        }

        // ---- epilogue(t): gate + plain f16x2 store into CSR slot ----
        #pragma unroll
        for (int rt = 0; rt < 2; rt++) {
            const f32x16 A = rt ? acc1 : acc0;
            #pragma unroll
            for (int g = 0; g < 4; g++) {
                const int4 sl4 = *(const int4*)(&sslot[cur][rt * 32 + g * 8 + khalf * 4]);
                #pragma unroll
                for (int j = 0; j < 4; j++) {
                    const int reg = g * 4 + j;
                    const float z  = A[reg] + bv;
                    const float lr = z > 0.f ? z : NEG * z;
                    const float sgm = 1.f / (1.f + __expf(-z));
                    const float m  = lr * sgm;
                    const float o  = __shfl_xor(m, 1);
                    const int sl = ((const int*)&sl4)[j];
                    if (!(lane & 1)) {
                        fp16x2 hv = __builtin_amdgcn_cvt_pkrtz(m, o);
                        *(fp16x2*)(msg + (long long)sl * HH + col) = hv;
                    }
                }
            }
        }

        if (!hasNext) break;
        cur ^= 1; tile = nt; nt += NBLK;
    }
}

// ---------- Phase B: per-node contiguous segment reduce (1 wave / node) ----------
__global__ __launch_bounds__(256) void reduce_kernel(const __fp16* __restrict__ msg,
                                                     const unsigned* __restrict__ base,
                                                     const unsigned* __restrict__ cnt,
                                                     float* __restrict__ out)
{
    const int n    = blockIdx.x * 4 + (threadIdx.x >> 6);   // 12500 blocks, exact
    const int lane = threadIdx.x & 63;
    const unsigned st  = base[n];
    const unsigned deg = cnt[n];
    float a0 = 0.f, a1 = 0.f;
    unsigned j = 0;
    union { unsigned u; __fp16 h[2]; } w0, w1;
    for (; j + 2 <= deg; j += 2) {
        w0.u = *(const unsigned*)(msg + ((long long)(st + j)     * HH) + lane * 2);
        w1.u = *(const unsigned*)(msg + ((long long)(st + j + 1) * HH) + lane * 2);
        a0 += (float)w0.h[0] + (float)w1.h[0];
        a1 += (float)w0.h[1] + (float)w1.h[1];
    }
    if (j < deg) {
        w0.u = *(const unsigned*)(msg + ((long long)(st + j) * HH) + lane * 2);
        a0 += (float)w0.h[0];
        a1 += (float)w0.h[1];
    }
    *(float2*)(out + (long long)n * HH + lane * 2) = float2{a0, a1};
}

// ---------- mid fallback (R7): atomic f16 accumulate ----------
__global__ __launch_bounds__(256, 3) void fused_pipe_kernel(
    const ushort* __restrict__ featb, const float* __restrict__ gdf,
    const float*  __restrict__ W,     const float* __restrict__ bias,
    const int*    __restrict__ src,   const int*   __restrict__ dst,
    __fp16* __restrict__ acc16)
{
    __shared__ char lds[64 * 640];
    __shared__ int  dsts[2][64];
    const int tid = threadIdx.x, lane = tid & 63, wid = tid >> 6;
    const int col = wid * 32 + (lane & 31), khalf = lane >> 5;
    const int r = tid >> 2, q = tid & 3;

    bf16x8 Wb[20];
    {
        const float* wrow = W + col * KK + khalf * 8;
        #pragma unroll
        for (int k = 0; k < 20; k++) {
            f32x4 x0 = *(const f32x4*)(wrow + k * 16);
            f32x4 x1 = *(const f32x4*)(wrow + k * 16 + 4);
            union { bf16x8 v; unsigned u[4]; } t;
            t.u[0] = pack2(x0[0], x0[1]); t.u[1] = pack2(x0[2], x0[3]);
            t.u[2] = pack2(x1[0], x1[1]); t.u[3] = pack2(x1[2], x1[3]);
            Wb[k] = t.v;
        }
    }
    const float bv = bias[col];
    int4 sf[8]; f32x4 sgv[4]; int dStage;

    auto issueLoads = [&](long long t, int s_i, int d_i) {
        const ushort* fs = featb + (long long)s_i * HH;
        const ushort* fd = featb + (long long)d_i * HH;
        const float*  ge = gdf + (t * 64 + r) * 64;
        #pragma unroll
        for (int i = 0; i < 8; i++) {
            const int c = q + i * 4;
            sf[i] = *(const int4*)((c < 16) ? (fs + c * 8) : (fd + (c - 16) * 8));
        }
        #pragma unroll
        for (int i = 0; i < 2; i++) {
            const int cg = q + i * 4;
            sgv[2 * i]     = *(const f32x4*)(ge + cg * 8);
            sgv[2 * i + 1] = *(const f32x4*)(ge + cg * 8 + 4);
        }
    };
    auto writeStage = [&](int buf) {
        const int xr = (r & 7) << 4;
        #pragma unroll
        for (int i = 0; i < 8; i++) {
            const int c = q + i * 4;
            *(int4*)(lds + r * 640 + ((c * 16) ^ xr)) = sf[i];
        }
        #pragma unroll
        for (int i = 0; i < 2; i++) {
            const int c = 32 + q + i * 4;
            int4 h;
            h.x = (int)pack2(sgv[2*i][0], sgv[2*i][1]);
            h.y = (int)pack2(sgv[2*i][2], sgv[2*i][3]);
            h.z = (int)pack2(sgv[2*i+1][0], sgv[2*i+1][1]);
            h.w = (int)pack2(sgv[2*i+1][2], sgv[2*i+1][3]);
            *(int4*)(lds + r * 640 + ((c * 16) ^ xr)) = h;
        }
        if (q == 0) dsts[buf][r] = dStage;
    };

    int tile = blockIdx.x;
    {
        int s0 = src[(long long)tile * 64 + r];
        int d0 = dst[(long long)tile * 64 + r];
        issueLoads(tile, s0, d0);
        dStage = d0;
    }
    int nt = tile + NBLK;
    int sN, dN;
    {
        const long long tc = (nt < NTILES) ? nt : 0;
        sN = src[tc * 64 + r]; dN = dst[tc * 64 + r];
    }
    writeStage(0);
    asm volatile("s_waitcnt lgkmcnt(0)" ::: "memory");
    __builtin_amdgcn_sched_barrier(0);
    __builtin_amdgcn_s_barrier();

    const int arow = lane & 31, xa = (arow & 7) << 4;
    int cur = 0;
    while (true) {
        const bool hasNext = (nt < NTILES);
        if (hasNext) {
            issueLoads(nt, sN, dN);
            dStage = dN;
            const long long tc = (nt + NBLK < NTILES) ? (long long)(nt + NBLK) : 0;
            sN = src[tc * 64 + r]; dN = dst[tc * 64 + r];
        }
        f32x16 acc0 = {}; f32x16 acc1 = {};
        #pragma unroll
        for (int k = 0; k < 20; k++) {
            const int kb = k * 32 + khalf * 16;
            bf16x8 a0 = *(const bf16x8*)(lds + arow * 640 + (kb ^ xa));
            bf16x8 a1 = *(const bf16x8*)(lds + (arow + 32) * 640 + (kb ^ xa));
            acc0 = __builtin_amdgcn_mfma_f32_32x32x16_bf16(a0, Wb[k], acc0, 0, 0, 0);
            acc1 = __builtin_amdgcn_mfma_f32_32x32x16_bf16(a1, Wb[k], acc1, 0, 0, 0);
        }
        if (hasNext) {
            __builtin_amdgcn_s_barrier();
            __builtin_amdgcn_sched_barrier(0);
            writeStage(cur ^ 1);
            asm volatile("s_waitcnt lgkmcnt(0)" ::: "memory");
            __builtin_amdgcn_sched_barrier(0);
            __builtin_amdgcn_s_barrier();
        }
        #pragma unroll
        for (int rt = 0; rt < 2; rt++) {
            const f32x16 A = rt ? acc1 : acc0;
            #pragma unroll
            for (int g = 0; g < 4; g++) {
                const int4 dn4 = *(const int4*)(&dsts[cur][rt * 32 + g * 8 + khalf * 4]);
                #pragma unroll
                for (int j = 0; j < 4; j++) {
                    const int reg = g * 4 + j;
                    const float z  = A[reg] + bv;
                    const float lr = z > 0.f ? z : NEG * z;
                    const float sgm = 1.f / (1.f + __expf(-z));
                    const float m  = lr * sgm;
                    const float o  = __shfl_xor(m, 1);
                    const int dn = ((const int*)&dn4)[j];
                    if (!(lane & 1)) {
                        fp16x2 hv = __builtin_amdgcn_cvt_pkrtz(m, o);
                        __fp16* p = acc16 + (long long)dn * HH + col;
                        asm volatile("global_atomic_pk_add_f16 %0, %1, off"
                                     :: "v"(p), "v"(hv) : "memory");
                    }
                }
            }
        }
        if (!hasNext) break;
        cur ^= 1; tile = nt; nt += NBLK;
    }
}

__global__ __launch_bounds__(256) void conv_kernel(const int4* __restrict__ acc,
                                                   float4* __restrict__ out)
{
    const int i = blockIdx.x * 256 + threadIdx.x;
    union { int4 v; __fp16 h[8]; } u;
    u.v = acc[i];
    float4 a, b;
    a.x = (float)u.h[0]; a.y = (float)u.h[1]; a.z = (float)u.h[2]; a.w = (float)u.h[3];
    b.x = (float)u.h[4]; b.y = (float)u.h[5]; b.z = (float)u.h[6]; b.w = (float)u.h[7];
    out[2 * i]     = a;
    out[2 * i + 1] = b;
}

// ---------- low fallback: f32 atomics straight into out ----------
__global__ __launch_bounds__(256) void fused_fallback_kernel(
    const float* __restrict__ feat, const float* __restrict__ gdf,
    const float* __restrict__ W,    const float* __restrict__ bias,
    const int*   __restrict__ src,  const int*   __restrict__ dst,
    float* __restrict__ out)
{
    __shared__ int4 lds4[64 * 40];
    __shared__ int  dsts[64];
    char* lds = (char*)lds4;
    const int tid = threadIdx.x, lane = tid & 63, wid = tid >> 6;
    const int col = wid * 32 + (lane & 31), khalf = lane >> 5;
    const int r = tid >> 2, q = tid & 3;
    const long long ebase = (long long)blockIdx.x * 64;

    bf16x8 Wb[20];
    {
        const float* wrow = W + col * KK + khalf * 8;
        #pragma unroll
        for (int k = 0; k < 20; k++) {
            f32x4 x0 = *(const f32x4*)(wrow + k * 16);
            f32x4 x1 = *(const f32x4*)(wrow + k * 16 + 4);
            union { bf16x8 v; unsigned u[4]; } t;
            t.u[0] = pack2(x0[0], x0[1]); t.u[1] = pack2(x0[2], x0[3]);
            t.u[2] = pack2(x1[0], x1[1]); t.u[3] = pack2(x1[2], x1[3]);
            Wb[k] = t.v;
        }
    }
    const int s = src[ebase + r], d = dst[ebase + r];
    if (q == 0) dsts[r] = d;
    {
        const float* fs = feat + (long long)s * HH;
        const float* fd = feat + (long long)d * HH;
        const float* ge = gdf + (ebase + r) * 64;
        #pragma unroll
        for (int i = 0; i < 10; i++) {
            const int c = q + i * 4;
            const float* p = (c < 16) ? (fs + c * 8)
                           : (c < 32) ? (fd + (c - 16) * 8)
                                      : (ge + (c - 32) * 8);
            f32x4 v0 = *(const f32x4*)p;
            f32x4 v1 = *(const f32x4*)(p + 4);
            int4 h;
            h.x = (int)pack2(v0[0], v0[1]); h.y = (int)pack2(v0[2], v0[3]);
            h.z = (int)pack2(v1[0], v1[1]); h.w = (int)pack2(v1[2], v1[3]);
            *(int4*)(lds + r * 640 + ((c * 16) ^ ((r & 7) << 4))) = h;
        }
    }
    __syncthreads();
    f32x16 acc0 = {}; f32x16 acc1 = {};
    const int arow = lane & 31, xa = (arow & 7) << 4;
    #pragma unroll
    for (int k = 0; k < 20; k++) {
        const int kb = k * 32 + khalf * 16;
        bf16x8 a0 = *(const bf16x8*)(lds + arow * 640 + (kb ^ xa));
        bf16x8 a1 = *(const bf16x8*)(lds + (arow + 32) * 640 + (kb ^ xa));
        acc0 = __builtin_amdgcn_mfma_f32_32x32x16_bf16(a0, Wb[k], acc0, 0, 0, 0);
        acc1 = __builtin_amdgcn_mfma_f32_32x32x16_bf16(a1, Wb[k], acc1, 0, 0, 0);
    }
    const float bv = bias[col];
    #pragma unroll
    for (int rt = 0; rt < 2; rt++) {
        const f32x16 A = rt ? acc1 : acc0;
        #pragma unroll
        for (int g = 0; g < 4; g++) {
            #pragma unroll
            for (int j = 0; j < 4; j++) {
                const int reg = g * 4 + j;
                const int row = j + g * 8 + khalf * 4;
                const float z  = A[reg] + bv;
                const float lr = z > 0.f ? z : NEG * z;
                const float sgm = 1.f / (1.f + __expf(-z));
                unsafeAtomicAdd(out + (long long)dsts[rt * 32 + row] * HH + col, lr * sgm);
            }
        }
    }
}

extern "C" void kernel_launch(void* const* d_in, const int* in_sizes, int n_in,
                              void* d_out, int out_size, void* d_ws, size_t ws_size,
                              hipStream_t stream) {
    const float* feat = (const float*)d_in[0];
    const float* gdf  = (const float*)d_in[1];
    const float* W    = (const float*)d_in[2];
    const float* bias = (const float*)d_in[3];
    const int*   src  = (const int*)d_in[4];
    const int*   dst  = (const int*)d_in[5];
    float* out = (float*)d_out;

    char* wsb = (char*)d_ws;
    // full-path layout
    __fp16*   msg    = (__fp16*)wsb;
    ushort*   featb  = (ushort*)(wsb + MSG_BYTES);
    int*      slot   = (int*)(wsb + MSG_BYTES + FEATB_BYTES);
    unsigned* cnt    = (unsigned*)(wsb + MSG_BYTES + FEATB_BYTES + SLOT_BYTES);
    unsigned* base   = cnt + 50176;
    unsigned* cursor = base + 50176;
    unsigned* bsum   = cursor + 50176;
    const size_t fullBytes = MSG_BYTES + FEATB_BYTES + SLOT_BYTES + 3 * CNT_BYTES + 1024;

    if (ws_size >= fullBytes) {
        (void)hipMemsetAsync(cnt, 0, 3 * CNT_BYTES + 1024, stream);
        featcvt_kernel<<<NN * HH / 8 / 256, 256, 0, stream>>>(feat, featb);
        hist_kernel<<<EE / 256, 256, 0, stream>>>(dst, cnt);
        scan1_kernel<<<NSB, 256, 0, stream>>>(cnt, base, bsum);
        scan2_kernel<<<1, 256, 0, stream>>>(bsum);
        scan3_kernel<<<NSB, 256, 0, stream>>>(base, bsum);
        slot_kernel<<<EE / 256, 256, 0, stream>>>(dst, base, cursor, slot);
        fused_store_kernel<<<NBLK, 256, 0, stream>>>(featb, gdf, W, bias,
                                                     src, dst, slot, msg);
        reduce_kernel<<<NN / 4, 256, 0, stream>>>(msg, base, cnt, out);
    } else if (ws_size >= 2 * ACC_BYTES) {
        __fp16* acc16 = (__fp16*)d_ws;
        ushort* fb2   = (ushort*)(wsb + ACC_BYTES);
        (void)hipMemsetAsync(d_ws, 0, ACC_BYTES, stream);
        featcvt_kernel<<<NN * HH / 8 / 256, 256, 0, stream>>>(feat, fb2);
        fused_pipe_kernel<<<NBLK, 256, 0, stream>>>(fb2, gdf, W, bias,
                                                    src, dst, acc16);
        conv_kernel<<<NN * HH / 8 / 256, 256, 0, stream>>>((const int4*)d_ws,
                                                           (float4*)out);
    } else {
        (void)hipMemsetAsync(out, 0, (size_t)out_size * sizeof(float), stream);
        fused_fallback_kernel<<<EE / 64, 256, 0, stream>>>(feat, gdf, W, bias,
                                                           src, dst, out);
    }
}

// Round 9
// 359.900 us; speedup vs baseline: 1.4058x; 1.4058x over previous
//
#include <hip/hip_runtime.h>
#include <hip/hip_bf16.h>

typedef __attribute__((ext_vector_type(8)))  short bf16x8;
typedef __attribute__((ext_vector_type(16))) float f32x16;
typedef __attribute__((ext_vector_type(4)))  float f32x4;
typedef __attribute__((ext_vector_type(2)))  __fp16 fp16x2;

#define NN 50000
#define EE 800000
#define HH 128
#define KK 320   /* 2H + B */
#define NEG 0.01f
#define NTILES (EE / 64)
#define NBLK 768            /* 256 CU x 3 resident blocks */
#define NSB 196             /* scan blocks: ceil(50000/256) */

#define ACC_BYTES   ((size_t)NN * HH * 2)        /* 12.8 MB f16 accumulator */
#define FEATB_BYTES ((size_t)NN * HH * 2)        /* 12.8 MB bf16 feat      */
#define PERM_BYTES  ((size_t)EE * 4)             /* 3.2 MB                 */
#define CNT_BYTES   ((size_t)50176 * 4)          /* padded to 256 blocks   */

__device__ __forceinline__ unsigned pack2(float a, float b) {
    unsigned short lo = __builtin_bit_cast(unsigned short, __float2bfloat16(a));
    unsigned short hi = __builtin_bit_cast(unsigned short, __float2bfloat16(b));
    return (unsigned)lo | ((unsigned)hi << 16);
}

// ---------- feat f32 -> bf16 (3125 blocks x 256, exact) ----------
__global__ __launch_bounds__(256) void featcvt_kernel(const float* __restrict__ feat,
                                                      ushort* __restrict__ featb)
{
    const int t = blockIdx.x * 256 + threadIdx.x;
    const float* p = feat + (long long)t * 8;
    f32x4 v0 = *(const f32x4*)p;
    f32x4 v1 = *(const f32x4*)(p + 4);
    int4 h;
    h.x = (int)pack2(v0[0], v0[1]); h.y = (int)pack2(v0[2], v0[3]);
    h.z = (int)pack2(v1[0], v1[1]); h.w = (int)pack2(v1[2], v1[3]);
    *(int4*)(featb + (long long)t * 8) = h;
}

// ---------- CSR sort by dst (proven in R8) ----------
__global__ __launch_bounds__(256) void hist_kernel(const int* __restrict__ dst,
                                                   unsigned* __restrict__ cnt)
{
    const int e = blockIdx.x * 256 + threadIdx.x;   // 3125 blocks, exact
    atomicAdd(&cnt[dst[e]], 1u);
}

__global__ __launch_bounds__(256) void scan1_kernel(const unsigned* __restrict__ cnt,
                                                    unsigned* __restrict__ base,
                                                    unsigned* __restrict__ bsum)
{
    __shared__ unsigned s[256];
    const int tid = threadIdx.x;
    const int g = blockIdx.x * 256 + tid;
    unsigned v = (g < NN) ? cnt[g] : 0u;
    s[tid] = v; __syncthreads();
    #pragma unroll
    for (int o = 1; o < 256; o <<= 1) {
        unsigned t = (tid >= o) ? s[tid - o] : 0u;
        __syncthreads();
        if (tid >= o) s[tid] += t;
        __syncthreads();
    }
    if (g < NN) base[g] = s[tid] - v;        // exclusive
    if (tid == 255) bsum[blockIdx.x] = s[255];
}

__global__ __launch_bounds__(256) void scan2_kernel(unsigned* __restrict__ bsum)
{
    __shared__ unsigned s[256];
    const int tid = threadIdx.x;
    unsigned v = (tid < NSB) ? bsum[tid] : 0u;
    s[tid] = v; __syncthreads();
    #pragma unroll
    for (int o = 1; o < 256; o <<= 1) {
        unsigned t = (tid >= o) ? s[tid - o] : 0u;
        __syncthreads();
        if (tid >= o) s[tid] += t;
        __syncthreads();
    }
    if (tid < NSB) bsum[tid] = s[tid] - v;   // exclusive block offsets
}

__global__ __launch_bounds__(256) void scan3_kernel(unsigned* __restrict__ base,
                                                    const unsigned* __restrict__ bsum)
{
    const int g = blockIdx.x * 256 + threadIdx.x;
    if (g < NN) base[g] += bsum[blockIdx.x];
}

__global__ __launch_bounds__(256) void permbuild_kernel(const int* __restrict__ dst,
                                                        const unsigned* __restrict__ base,
                                                        unsigned* __restrict__ cursor,
                                                        int* __restrict__ perm)
{
    const int e = blockIdx.x * 256 + threadIdx.x;   // 3125 blocks, exact
    const int d = dst[e];
    const unsigned rank = atomicAdd(&cursor[d], 1u);
    perm[base[d] + rank] = e;
}

// ---------- main: dst-sorted tiles, contiguous chunks, XCD-sliced ----------
// Each block owns a CONTIGUOUS run of sorted tiles; XCD swizzle maps each XCD
// to a contiguous 1/8 of the dst range so featb[dst] + acc16 slice stay in
// that XCD's L2. Register run-merging cuts atomics ~4x; f32 pre-accumulate.
__global__ __launch_bounds__(256, 3) void fused_sorted_kernel(
    const ushort* __restrict__ featb, const float* __restrict__ gdf,
    const float*  __restrict__ W,     const float* __restrict__ bias,
    const int*    __restrict__ src,   const int*   __restrict__ dst,
    const int*    __restrict__ perm,  __fp16* __restrict__ acc16)
{
    __shared__ char lds[64 * 640];   // 40960B tile
    __shared__ int  dsts[64];

    const int tid  = threadIdx.x;
    const int lane = tid & 63;
    const int wid  = tid >> 6;
    const int col  = wid * 32 + (lane & 31);
    const int khalf = lane >> 5;
    const int r = tid >> 2, q = tid & 3;     // 4 threads per edge row (staging)

    // ---- W fragments (f32 -> bf16, register-resident, loaded once) ----
    bf16x8 Wb[20];
    {
        const float* wrow = W + col * KK + khalf * 8;
        #pragma unroll
        for (int k = 0; k < 20; k++) {
            f32x4 x0 = *(const f32x4*)(wrow + k * 16);
            f32x4 x1 = *(const f32x4*)(wrow + k * 16 + 4);
            union { bf16x8 v; unsigned u[4]; } t;
            t.u[0] = pack2(x0[0], x0[1]); t.u[1] = pack2(x0[2], x0[3]);
            t.u[2] = pack2(x1[0], x1[1]); t.u[3] = pack2(x1[2], x1[3]);
            Wb[k] = t.v;
        }
    }
    const float bv = bias[col];

    // ---- contiguous chunk of sorted tiles, XCD-sliced ----
    const int xcd = blockIdx.x & 7, wI = blockIdx.x >> 3;
    const int cid = xcd * (NBLK / 8) + wI;            // 0..767 contiguous
    const int qc  = NTILES / NBLK;                    // 16
    const int rem = NTILES % NBLK;                    // 212
    const int t0  = cid * qc + (cid < rem ? cid : rem);
    const int len = qc + (cid < rem ? 1 : 0);

    // prefetched indices for current tile
    int eCur, sCur, dCur;
    {
        const long long p = (long long)t0 * 64 + r;
        eCur = perm[p]; sCur = src[eCur]; dCur = dst[eCur];
    }

    const int arow = lane & 31;
    const int xa   = (arow & 7) << 4;

    auto flush = [&](int dn, float v) {
        const float o = __shfl_xor(v, 1);
        if (!(lane & 1)) {
            fp16x2 hv = __builtin_amdgcn_cvt_pkrtz(v, o);
            __fp16* pa = acc16 + (long long)dn * HH + col;
            asm volatile("global_atomic_pk_add_f16 %0, %1, off"
                         :: "v"(pa), "v"(hv) : "memory");
        }
    };

    for (int t = t0; t < t0 + len; ++t) {
        // ---- stage tile t: [featb[src] | featb[dst] | gdf->bf16] ----
        if (q == 0) dsts[r] = dCur;
        {
            const ushort* fs = featb + (long long)sCur * HH;
            const ushort* fd = featb + (long long)dCur * HH;
            const float*  ge = gdf + (long long)eCur * 64;
            const int xr = (r & 7) << 4;
            #pragma unroll
            for (int i = 0; i < 8; i++) {            // bf16 feat, direct 16B copies
                const int c = q + i * 4;
                int4 h = *(const int4*)((c < 16) ? (fs + c * 8) : (fd + (c - 16) * 8));
                *(int4*)(lds + r * 640 + ((c * 16) ^ xr)) = h;
            }
            #pragma unroll
            for (int i = 8; i < 10; i++) {           // gdf f32 -> bf16
                const int c = q + i * 4;
                const float* p = ge + (c - 32) * 8;
                f32x4 v0 = *(const f32x4*)p;
                f32x4 v1 = *(const f32x4*)(p + 4);
                int4 h;
                h.x = (int)pack2(v0[0], v0[1]); h.y = (int)pack2(v0[2], v0[3]);
                h.z = (int)pack2(v1[0], v1[1]); h.w = (int)pack2(v1[2], v1[3]);
                *(int4*)(lds + r * 640 + ((c * 16) ^ xr)) = h;
            }
        }
        // prefetch next tile's indices (hidden under barrier+MFMA)
        if (t + 1 < t0 + len) {
            const long long p = (long long)(t + 1) * 64 + r;
            eCur = perm[p]; sCur = src[eCur]; dCur = dst[eCur];
        }
        __syncthreads();

        // ---- MFMA: D[64 x 32cols] += A[64 x 320] * W^T slice ----
        f32x16 acc0 = {}; f32x16 acc1 = {};
        #pragma unroll
        for (int k = 0; k < 20; k++) {
            const int kb = k * 32 + khalf * 16;
            bf16x8 a0 = *(const bf16x8*)(lds + arow * 640 + (kb ^ xa));
            bf16x8 a1 = *(const bf16x8*)(lds + (arow + 32) * 640 + (kb ^ xa));
            acc0 = __builtin_amdgcn_mfma_f32_32x32x16_bf16(a0, Wb[k], acc0, 0, 0, 0);
            acc1 = __builtin_amdgcn_mfma_f32_32x32x16_bf16(a1, Wb[k], acc1, 0, 0, 0);
        }

        // ---- epilogue: gate + run-merged packed f16 atomics ----
        #pragma unroll
        for (int rt = 0; rt < 2; rt++) {
            const f32x16 A = rt ? acc1 : acc0;
            #pragma unroll
            for (int g = 0; g < 4; g++) {
                const int4 dn4 = *(const int4*)(&dsts[rt * 32 + g * 8 + khalf * 4]);
                const int dd[4] = { dn4.x, dn4.y, dn4.z, dn4.w };   // rows j..j+3 consecutive
                float mm[4];
                #pragma unroll
                for (int j = 0; j < 4; j++) {
                    const float z  = A[g * 4 + j] + bv;
                    const float lr = z > 0.f ? z : NEG * z;
                    mm[j] = lr / (1.f + __expf(-z));
                }
                float s = mm[0];
                #pragma unroll
                for (int j = 1; j < 4; j++) {
                    if (dd[j] == dd[j - 1]) s += mm[j];
                    else { flush(dd[j - 1], s); s = mm[j]; }
                }
                flush(dd[3], s);
            }
        }
        __syncthreads();   // protect lds/dsts before next staging
    }
}

// ---------- acc16 -> f32 out ----------
__global__ __launch_bounds__(256) void conv_kernel(const int4* __restrict__ acc,
                                                   float4* __restrict__ out)
{
    const int i = blockIdx.x * 256 + threadIdx.x;   // exactly 800000 threads
    union { int4 v; __fp16 h[8]; } u;
    u.v = acc[i];
    float4 a, b;
    a.x = (float)u.h[0]; a.y = (float)u.h[1]; a.z = (float)u.h[2]; a.w = (float)u.h[3];
    b.x = (float)u.h[4]; b.y = (float)u.h[5]; b.z = (float)u.h[6]; b.w = (float)u.h[7];
    out[2 * i]     = a;
    out[2 * i + 1] = b;
}

// ---------- fallback (small ws): f32 atomics straight into out ----------
__global__ __launch_bounds__(256) void fused_fallback_kernel(
    const float* __restrict__ feat, const float* __restrict__ gdf,
    const float* __restrict__ W,    const float* __restrict__ bias,
    const int*   __restrict__ src,  const int*   __restrict__ dst,
    float* __restrict__ out)
{
    __shared__ int4 lds4[64 * 40];
    __shared__ int  dsts[64];
    char* lds = (char*)lds4;
    const int tid = threadIdx.x, lane = tid & 63, wid = tid >> 6;
    const int col = wid * 32 + (lane & 31), khalf = lane >> 5;
    const int r = tid >> 2, q = tid & 3;
    const long long ebase = (long long)blockIdx.x * 64;

    bf16x8 Wb[20];
    {
        const float* wrow = W + col * KK + khalf * 8;
        #pragma unroll
        for (int k = 0; k < 20; k++) {
            f32x4 x0 = *(const f32x4*)(wrow + k * 16);
            f32x4 x1 = *(const f32x4*)(wrow + k * 16 + 4);
            union { bf16x8 v; unsigned u[4]; } t;
            t.u[0] = pack2(x0[0], x0[1]); t.u[1] = pack2(x0[2], x0[3]);
            t.u[2] = pack2(x1[0], x1[1]); t.u[3] = pack2(x1[2], x1[3]);
            Wb[k] = t.v;
        }
    }
    const int s = src[ebase + r], d = dst[ebase + r];
    if (q == 0) dsts[r] = d;
    {
        const float* fs = feat + (long long)s * HH;
        const float* fd = feat + (long long)d * HH;
        const float* ge = gdf + (ebase + r) * 64;
        #pragma unroll
        for (int i = 0; i < 10; i++) {
            const int c = q + i * 4;
            const float* p = (c < 16) ? (fs + c * 8)
                           : (c < 32) ? (fd + (c - 16) * 8)
                                      : (ge + (c - 32) * 8);
            f32x4 v0 = *(const f32x4*)p;
            f32x4 v1 = *(const f32x4*)(p + 4);
            int4 h;
            h.x = (int)pack2(v0[0], v0[1]); h.y = (int)pack2(v0[2], v0[3]);
            h.z = (int)pack2(v1[0], v1[1]); h.w = (int)pack2(v1[2], v1[3]);
            *(int4*)(lds + r * 640 + ((c * 16) ^ ((r & 7) << 4))) = h;
        }
    }
    __syncthreads();
    f32x16 acc0 = {}; f32x16 acc1 = {};
    const int arow = lane & 31, xa = (arow & 7) << 4;
    #pragma unroll
    for (int k = 0; k < 20; k++) {
        const int kb = k * 32 + khalf * 16;
        bf16x8 a0 = *(const bf16x8*)(lds + arow * 640 + (kb ^ xa));
        bf16x8 a1 = *(const bf16x8*)(lds + (arow + 32) * 640 + (kb ^ xa));
        acc0 = __builtin_amdgcn_mfma_f32_32x32x16_bf16(a0, Wb[k], acc0, 0, 0, 0);
        acc1 = __builtin_amdgcn_mfma_f32_32x32x16_bf16(a1, Wb[k], acc1, 0, 0, 0);
    }
    const float bv = bias[col];
    #pragma unroll
    for (int rt = 0; rt < 2; rt++) {
        const f32x16 A = rt ? acc1 : acc0;
        #pragma unroll
        for (int g = 0; g < 4; g++) {
            #pragma unroll
            for (int j = 0; j < 4; j++) {
                const int reg = g * 4 + j;
                const int row = j + g * 8 + khalf * 4;
                const float z  = A[reg] + bv;
                const float lr = z > 0.f ? z : NEG * z;
                const float sgm = 1.f / (1.f + __expf(-z));
                unsafeAtomicAdd(out + (long long)dsts[rt * 32 + row] * HH + col, lr * sgm);
            }
        }
    }
}

extern "C" void kernel_launch(void* const* d_in, const int* in_sizes, int n_in,
                              void* d_out, int out_size, void* d_ws, size_t ws_size,
                              hipStream_t stream) {
    const float* feat = (const float*)d_in[0];
    const float* gdf  = (const float*)d_in[1];
    const float* W    = (const float*)d_in[2];
    const float* bias = (const float*)d_in[3];
    const int*   src  = (const int*)d_in[4];
    const int*   dst  = (const int*)d_in[5];
    float* out = (float*)d_out;

    char* wsb = (char*)d_ws;
    __fp16*   acc16  = (__fp16*)wsb;
    ushort*   featb  = (ushort*)(wsb + ACC_BYTES);
    int*      perm   = (int*)(wsb + ACC_BYTES + FEATB_BYTES);
    unsigned* cnt    = (unsigned*)(wsb + ACC_BYTES + FEATB_BYTES + PERM_BYTES);
    unsigned* base   = cnt + 50176;
    unsigned* cursor = base + 50176;
    unsigned* bsum   = cursor + 50176;
    const size_t fullBytes = ACC_BYTES + FEATB_BYTES + PERM_BYTES + 3 * CNT_BYTES + 4096;

    if (ws_size >= fullBytes) {
        (void)hipMemsetAsync(acc16, 0, ACC_BYTES, stream);           // f16 accumulator
        (void)hipMemsetAsync(cnt, 0, CNT_BYTES, stream);             // hist counts
        (void)hipMemsetAsync(cursor, 0, CNT_BYTES + 4096, stream);   // cursors + bsum
        featcvt_kernel<<<NN * HH / 8 / 256, 256, 0, stream>>>(feat, featb);
        hist_kernel<<<EE / 256, 256, 0, stream>>>(dst, cnt);
        scan1_kernel<<<NSB, 256, 0, stream>>>(cnt, base, bsum);
        scan2_kernel<<<1, 256, 0, stream>>>(bsum);
        scan3_kernel<<<NSB, 256, 0, stream>>>(base, bsum);
        permbuild_kernel<<<EE / 256, 256, 0, stream>>>(dst, base, cursor, perm);
        fused_sorted_kernel<<<NBLK, 256, 0, stream>>>(featb, gdf, W, bias,
                                                      src, dst, perm, acc16);
        conv_kernel<<<NN * HH / 8 / 256, 256, 0, stream>>>((const int4*)acc16,
                                                           (float4*)out);
    } else {
        (void)hipMemsetAsync(out, 0, (size_t)out_size * sizeof(float), stream);
        fused_fallback_kernel<<<EE / 64, 256, 0, stream>>>(feat, gdf, W, bias,
                                                           src, dst, out);
    }
}